// Round 4
// baseline (262.405 us; speedup 1.0000x reference)
//
#include <hip/hip_runtime.h>

#define NJ  21
#define HID 10
#define FT  6

// One thread per batch element. ZERO local arrays: rounds 2-3 proved the
// feat aggregates get demoted to scratch (VGPR=24/36, +264MB spill writes,
// latency-bound at 22% VALU / 34% HBM). All intermediates are macro-generated
// NAMED SCALARS -> no alloca exists -> nothing can spill to scratch.

// relu(dot10(W,x) + b), explicit fmaf tree
#define F10(W, Bv, a0,a1,a2,a3,a4,a5,a6,a7,a8,a9) \
  fmaxf(fmaf((W)[9],(a9),fmaf((W)[8],(a8),fmaf((W)[7],(a7),fmaf((W)[6],(a6), \
        fmaf((W)[5],(a5),fmaf((W)[4],(a4),fmaf((W)[3],(a3),fmaf((W)[2],(a2), \
        fmaf((W)[1],(a1),fmaf((W)[0],(a0),(Bv))))))))))), 0.0f)

// hidden row r of joint j (parent feature scalars fP_*)
#define HROW(N,P,j,r) const float h##N##_##r = F10(W1 + ((j)-1)*100 + (r)*10, \
  b1[((j)-1)*10 + (r)], \
  q##N.x, q##N.y, q##N.z, q##N.w, \
  f##P##_0, f##P##_1, f##P##_2, f##P##_3, f##P##_4, f##P##_5);

// output row r of joint j (from hidden scalars hN_*)
#define FROW(N,j,r) const float f##N##_##r = F10(W2 + (j)*60 + (r)*10, \
  b2[(j)*6 + (r)], \
  h##N##_0, h##N##_1, h##N##_2, h##N##_3, h##N##_4, \
  h##N##_5, h##N##_6, h##N##_7, h##N##_8, h##N##_9);

#define STORE_F(N,j) { \
  float2* o2 = reinterpret_cast<float2*>(op + (j)*FT); \
  o2[0] = make_float2(f##N##_0, f##N##_1); \
  o2[1] = make_float2(f##N##_2, f##N##_3); \
  o2[2] = make_float2(f##N##_4, f##N##_5); }

#define DO_JOINT(j,P,N) \
  const float4 q##N = qv[j]; \
  HROW(N,P,j,0) HROW(N,P,j,1) HROW(N,P,j,2) HROW(N,P,j,3) HROW(N,P,j,4) \
  HROW(N,P,j,5) HROW(N,P,j,6) HROW(N,P,j,7) HROW(N,P,j,8) HROW(N,P,j,9) \
  FROW(N,j,0) FROW(N,j,1) FROW(N,j,2) FROW(N,j,3) FROW(N,j,4) FROW(N,j,5) \
  STORE_F(N,j)

__global__ __launch_bounds__(256, 4) void se_kernel(
    const float* __restrict__ quat,   // [B, 21, 4]
    const float* __restrict__ W1r,    // [10, 4]
    const float* __restrict__ b1r,    // [10]
    const float* __restrict__ W1,     // [20, 10, 10]
    const float* __restrict__ b1,     // [20, 10]
    const float* __restrict__ W2,     // [21, 6, 10]
    const float* __restrict__ b2,     // [21, 6]
    float*       __restrict__ out,    // [B, 126]
    int B)
{
    const int b = blockIdx.x * blockDim.x + threadIdx.x;
    if (b >= B) return;

    const float4* __restrict__ qv = reinterpret_cast<const float4*>(quat) + (size_t)b * NJ;
    float* __restrict__ op = out + (size_t)b * (NJ * FT);

    // ---- root (joint 0): in = quat[b,0,:] only ----
    const float4 q0 = qv[0];
#define H0ROW(r) const float h0_##r = fmaxf( \
    fmaf(W1r[(r)*4+3], q0.w, fmaf(W1r[(r)*4+2], q0.z, \
    fmaf(W1r[(r)*4+1], q0.y, fmaf(W1r[(r)*4+0], q0.x, b1r[r])))), 0.0f);
    H0ROW(0) H0ROW(1) H0ROW(2) H0ROW(3) H0ROW(4)
    H0ROW(5) H0ROW(6) H0ROW(7) H0ROW(8) H0ROW(9)
#undef H0ROW
    FROW(0,0,0) FROW(0,0,1) FROW(0,0,2) FROW(0,0,3) FROW(0,0,4) FROW(0,0,5)
    STORE_F(0,0)

    // ---- DFS over the kinematic tree (<=3 parent feature sets live) ----
    DO_JOINT(1,0,1)    DO_JOINT(4,1,4)    DO_JOINT(7,4,7)    DO_JOINT(10,7,10)
    DO_JOINT(2,0,2)    DO_JOINT(5,2,5)    DO_JOINT(8,5,8)    DO_JOINT(11,8,11)
    DO_JOINT(3,0,3)    DO_JOINT(6,3,6)    DO_JOINT(9,6,9)
    DO_JOINT(12,9,12)  DO_JOINT(15,12,15)
    DO_JOINT(13,9,13)  DO_JOINT(16,13,16) DO_JOINT(18,16,18) DO_JOINT(20,18,20)
    DO_JOINT(14,9,14)  DO_JOINT(17,14,17) DO_JOINT(19,17,19)
}

extern "C" void kernel_launch(void* const* d_in, const int* in_sizes, int n_in,
                              void* d_out, int out_size, void* d_ws, size_t ws_size,
                              hipStream_t stream) {
    const float* quat = (const float*)d_in[0];
    const float* W1r  = (const float*)d_in[1];
    const float* b1r  = (const float*)d_in[2];
    const float* W1   = (const float*)d_in[3];
    const float* b1   = (const float*)d_in[4];
    const float* W2   = (const float*)d_in[5];
    const float* b2   = (const float*)d_in[6];
    float* out = (float*)d_out;

    const int B = in_sizes[0] / (NJ * 4);
    const int threads = 256;
    const int blocks  = (B + threads - 1) / threads;
    se_kernel<<<blocks, threads, 0, stream>>>(quat, W1r, b1r, W1, b1, W2, b2, out, B);
}

// Round 5
// 207.880 us; speedup vs baseline: 1.2623x; 1.2623x over previous
//
#include <hip/hip_runtime.h>

#define NJ 21
#define FT 6
#define RS 43   // LDS row stride: 42 chunk floats + 1 pad; odd => conflict-free

// One thread per batch element; joints computed in index order (parent<child).
// Round-2..4 lesson: direct per-joint float2 stores at 504B lane stride keep
// 33MB/XCD of partially-dirty lines -> L2 evicts them -> ~2.1x write and
// ~1.4x read amplification, latency-bound at 22% VALU / 34% HBM.
// Fix: stage 7 joints' outputs (42 floats) per thread in LDS, flush with
// lane-contiguous cooperative stores so lines become fully dirty immediately.

#define F10(W, Bv, a0,a1,a2,a3,a4,a5,a6,a7,a8,a9) \
  fmaxf(fmaf((W)[9],(a9),fmaf((W)[8],(a8),fmaf((W)[7],(a7),fmaf((W)[6],(a6), \
        fmaf((W)[5],(a5),fmaf((W)[4],(a4),fmaf((W)[3],(a3),fmaf((W)[2],(a2), \
        fmaf((W)[1],(a1),fmaf((W)[0],(a0),(Bv))))))))))), 0.0f)

#define HROW(N,P,j,r) const float h##N##_##r = F10(W1 + ((j)-1)*100 + (r)*10, \
  b1[((j)-1)*10 + (r)], \
  q##N.x, q##N.y, q##N.z, q##N.w, \
  f##P##_0, f##P##_1, f##P##_2, f##P##_3, f##P##_4, f##P##_5);

#define FROW(N,j,r) const float f##N##_##r = F10(W2 + (j)*60 + (r)*10, \
  b2[(j)*6 + (r)], \
  h##N##_0, h##N##_1, h##N##_2, h##N##_3, h##N##_4, \
  h##N##_5, h##N##_6, h##N##_7, h##N##_8, h##N##_9);

// write joint's 6 outputs to this thread's LDS row (stride-43: bank-free)
#define PUT(N,jj) { float* tr = trow + (jj)*FT; \
  tr[0]=f##N##_0; tr[1]=f##N##_1; tr[2]=f##N##_2; \
  tr[3]=f##N##_3; tr[4]=f##N##_4; tr[5]=f##N##_5; }

#define DO_JOINT(j,P,N,jj) \
  const float4 q##N = qv[j]; \
  HROW(N,P,j,0) HROW(N,P,j,1) HROW(N,P,j,2) HROW(N,P,j,3) HROW(N,P,j,4) \
  HROW(N,P,j,5) HROW(N,P,j,6) HROW(N,P,j,7) HROW(N,P,j,8) HROW(N,P,j,9) \
  FROW(N,j,0) FROW(N,j,1) FROW(N,j,2) FROW(N,j,3) FROW(N,j,4) FROW(N,j,5) \
  PUT(N,jj)

// cooperative chunk flush: wave w writes rows [w*64, w*64+64); 42 lanes put
// one row's 42 floats contiguously (168B runs; lines become fully dirty fast)
#define FLUSH(k) { \
  __syncthreads(); \
  const int w_ = tid >> 6, lane_ = tid & 63; \
  if (lane_ < 42) { \
    _Pragma("unroll 8") \
    for (int r_ = w_*64; r_ < w_*64 + 64; ++r_) \
      out[(size_t)(base + r_)*126 + (k)*42 + lane_] = tile[r_*RS + lane_]; \
  } \
  __syncthreads(); }

__global__ __launch_bounds__(256) void se_kernel(
    const float* __restrict__ quat,   // [B, 21, 4]
    const float* __restrict__ W1r,    // [10, 4]
    const float* __restrict__ b1r,    // [10]
    const float* __restrict__ W1,     // [20, 10, 10]
    const float* __restrict__ b1,     // [20, 10]
    const float* __restrict__ W2,     // [21, 6, 10]
    const float* __restrict__ b2,     // [21, 6]
    float*       __restrict__ out,    // [B, 126]
    int B)
{
    __shared__ float tile[256 * RS];          // 44032 B -> 3 blocks/CU
    const int tid  = threadIdx.x;
    const int base = blockIdx.x * 256;

    const float4* __restrict__ qv =
        reinterpret_cast<const float4*>(quat) + (size_t)(base + tid) * NJ;
    float* __restrict__ trow = tile + tid * RS;

    // ---- chunk 0: joints 0..6 ----
    // root (joint 0): in = quat only
    const float4 q0 = qv[0];
#define H0ROW(r) const float h0_##r = fmaxf( \
    fmaf(W1r[(r)*4+3], q0.w, fmaf(W1r[(r)*4+2], q0.z, \
    fmaf(W1r[(r)*4+1], q0.y, fmaf(W1r[(r)*4+0], q0.x, b1r[r])))), 0.0f);
    H0ROW(0) H0ROW(1) H0ROW(2) H0ROW(3) H0ROW(4)
    H0ROW(5) H0ROW(6) H0ROW(7) H0ROW(8) H0ROW(9)
#undef H0ROW
    FROW(0,0,0) FROW(0,0,1) FROW(0,0,2) FROW(0,0,3) FROW(0,0,4) FROW(0,0,5)
    PUT(0,0)

    DO_JOINT(1,0,1,1)   DO_JOINT(2,0,2,2)   DO_JOINT(3,0,3,3)
    DO_JOINT(4,1,4,4)   DO_JOINT(5,2,5,5)   DO_JOINT(6,3,6,6)
    FLUSH(0)

    // ---- chunk 1: joints 7..13 ----
    DO_JOINT(7,4,7,0)   DO_JOINT(8,5,8,1)   DO_JOINT(9,6,9,2)
    DO_JOINT(10,7,10,3) DO_JOINT(11,8,11,4)
    DO_JOINT(12,9,12,5) DO_JOINT(13,9,13,6)
    FLUSH(1)

    // ---- chunk 2: joints 14..20 ----
    DO_JOINT(14,9,14,0)  DO_JOINT(15,12,15,1) DO_JOINT(16,13,16,2)
    DO_JOINT(17,14,17,3) DO_JOINT(18,16,18,4)
    DO_JOINT(19,17,19,5) DO_JOINT(20,18,20,6)
    FLUSH(2)
}

extern "C" void kernel_launch(void* const* d_in, const int* in_sizes, int n_in,
                              void* d_out, int out_size, void* d_ws, size_t ws_size,
                              hipStream_t stream) {
    const float* quat = (const float*)d_in[0];
    const float* W1r  = (const float*)d_in[1];
    const float* b1r  = (const float*)d_in[2];
    const float* W1   = (const float*)d_in[3];
    const float* b1   = (const float*)d_in[4];
    const float* W2   = (const float*)d_in[5];
    const float* b2   = (const float*)d_in[6];
    float* out = (float*)d_out;

    const int B = in_sizes[0] / (NJ * 4);
    const int threads = 256;
    const int blocks  = (B + threads - 1) / threads;
    se_kernel<<<blocks, threads, 0, stream>>>(quat, W1r, b1r, W1, b1, W2, b2, out, B);
}

// Round 6
// 203.773 us; speedup vs baseline: 1.2877x; 1.0202x over previous
//
#include <hip/hip_runtime.h>

#define NJ  21
#define FT  6
#define TRS 43   // output tile row stride (floats); odd -> bank-conflict-free
#define WRS 12   // weight row stride: 10 floats padded to 12 (48B, 16B-aligned)

// One thread per batch element; joints in index order (parent < child).
// Round-5 lesson: write path fixed (LDS tile flush, WRITE ~ideal) but still
// latency-bound at 25% VALU: ~3.4K cycles/joint vs ~350 issue cycles. The
// per-joint stall is the ~176 uniform weight loads -> s_load into a tiny
// SGPR budget (112 SGPRs) -> serialized issue/wait/fma chains.
// Fix: stage all weights/biases in LDS once per block; inner loops read them
// via uniform-address ds_read (broadcast, conflict-free, VGPR dst, deep
// lgkmcnt pipelining). Tile halved (2 x 128 rows) -> 39KB LDS, 4 blocks/CU.

#define F10(W, Bv, a0,a1,a2,a3,a4,a5,a6,a7,a8,a9) \
  fmaxf(fmaf((W)[9],(a9),fmaf((W)[8],(a8),fmaf((W)[7],(a7),fmaf((W)[6],(a6), \
        fmaf((W)[5],(a5),fmaf((W)[4],(a4),fmaf((W)[3],(a3),fmaf((W)[2],(a2), \
        fmaf((W)[1],(a1),fmaf((W)[0],(a0),(Bv))))))))))), 0.0f)

#define HROW(N,P,j,r) const float h##N##_##r = \
  F10(w1s + ((j)-1)*10*WRS + (r)*WRS, b1s[((j)-1)*10 + (r)], \
      q##N.x, q##N.y, q##N.z, q##N.w, \
      f##P##_0, f##P##_1, f##P##_2, f##P##_3, f##P##_4, f##P##_5);

#define FROW(N,j,r) const float f##N##_##r = \
  F10(w2s + (j)*6*WRS + (r)*WRS, b2s[(j)*6 + (r)], \
      h##N##_0, h##N##_1, h##N##_2, h##N##_3, h##N##_4, \
      h##N##_5, h##N##_6, h##N##_7, h##N##_8, h##N##_9);

#define DO_JOINT(j,P,N) \
  const float4 q##N = qv[j]; \
  HROW(N,P,j,0) HROW(N,P,j,1) HROW(N,P,j,2) HROW(N,P,j,3) HROW(N,P,j,4) \
  HROW(N,P,j,5) HROW(N,P,j,6) HROW(N,P,j,7) HROW(N,P,j,8) HROW(N,P,j,9) \
  FROW(N,j,0) FROW(N,j,1) FROW(N,j,2) FROW(N,j,3) FROW(N,j,4) FROW(N,j,5)

#define PUT6(p, N) { (p)[0]=f##N##_0; (p)[1]=f##N##_1; (p)[2]=f##N##_2; \
                     (p)[3]=f##N##_3; (p)[4]=f##N##_4; (p)[5]=f##N##_5; }

// Half-block flush: threads [half*128, half*128+128) dump 42 regs to tile,
// then ALL 256 threads cooperatively store 128 rows x 42 floats coalesced.
#define HALF_FLUSH(k, half, N0,N1,N2,N3,N4,N5,N6) \
  __syncthreads(); \
  if ((tid >> 7) == (half)) { \
    float* tr_ = tile + (tid & 127) * TRS; \
    PUT6(tr_+0,  N0) PUT6(tr_+6,  N1) PUT6(tr_+12, N2) PUT6(tr_+18, N3) \
    PUT6(tr_+24, N4) PUT6(tr_+30, N5) PUT6(tr_+36, N6) \
  } \
  __syncthreads(); \
  { const int lane_ = tid & 63, w_ = tid >> 6; \
    _Pragma("unroll") \
    for (int i_ = 0; i_ < 21; ++i_) { \
      const int idx_ = w_ * 1344 + i_ * 64 + lane_; \
      const int row_ = idx_ / 42, col_ = idx_ - row_ * 42; \
      const int rg_  = base + (half)*128 + row_; \
      if (rg_ < B) out[(size_t)rg_ * 126 + (k)*42 + col_] = tile[row_ * TRS + col_]; \
    } \
  }

#define CHUNK_FLUSH(k, N0,N1,N2,N3,N4,N5,N6) \
  HALF_FLUSH(k, 0, N0,N1,N2,N3,N4,N5,N6) \
  HALF_FLUSH(k, 1, N0,N1,N2,N3,N4,N5,N6)

__global__ __launch_bounds__(256, 4) void se_kernel(
    const float* __restrict__ quat,   // [B, 21, 4]
    const float* __restrict__ W1r,    // [10, 4]
    const float* __restrict__ b1r,    // [10]
    const float* __restrict__ W1,     // [20, 10, 10]
    const float* __restrict__ b1,     // [20, 10]
    const float* __restrict__ W2,     // [21, 6, 10]
    const float* __restrict__ b2,     // [21, 6]
    float*       __restrict__ out,    // [B, 126]
    int B)
{
    __shared__ __align__(16) float w1s[20*10*WRS];   // 9600 B
    __shared__ __align__(16) float w2s[21*6*WRS];    // 6048 B
    __shared__ float b1s[200], b2s[126], w1rs[40], b1rs[16];
    __shared__ float tile[128*TRS];                  // 22016 B  -> total ~39 KB

    const int tid  = threadIdx.x;
    const int base = blockIdx.x * 256;

    // ---- stage weights into LDS (once per block; global reads hit L2/LLC) ----
    for (int i = tid; i < 2000; i += 256) w1s[(i/10)*WRS + i%10] = W1[i];
    for (int i = tid; i < 1260; i += 256) w2s[(i/10)*WRS + i%10] = W2[i];
    for (int i = tid; i < 200;  i += 256) b1s[i] = b1[i];
    if (tid < 126) b2s[tid] = b2[tid];
    if (tid < 40)  w1rs[tid] = W1r[tid];
    if (tid < 10)  b1rs[tid] = b1r[tid];
    __syncthreads();

    const int bcl = min(base + tid, B - 1);          // clamp (full blocks here)
    const float4* __restrict__ qv =
        reinterpret_cast<const float4*>(quat) + (size_t)bcl * NJ;

    // ---- chunk 0: joints 0..6 ----
    const float4 q0 = qv[0];
#define H0ROW(r) const float h0_##r = fmaxf( \
    fmaf(w1rs[(r)*4+3], q0.w, fmaf(w1rs[(r)*4+2], q0.z, \
    fmaf(w1rs[(r)*4+1], q0.y, fmaf(w1rs[(r)*4+0], q0.x, b1rs[r])))), 0.0f);
    H0ROW(0) H0ROW(1) H0ROW(2) H0ROW(3) H0ROW(4)
    H0ROW(5) H0ROW(6) H0ROW(7) H0ROW(8) H0ROW(9)
#undef H0ROW
    FROW(0,0,0) FROW(0,0,1) FROW(0,0,2) FROW(0,0,3) FROW(0,0,4) FROW(0,0,5)

    DO_JOINT(1,0,1)  DO_JOINT(2,0,2)  DO_JOINT(3,0,3)
    DO_JOINT(4,1,4)  DO_JOINT(5,2,5)  DO_JOINT(6,3,6)
    CHUNK_FLUSH(0, 0,1,2,3,4,5,6)

    // ---- chunk 1: joints 7..13 ----
    DO_JOINT(7,4,7)   DO_JOINT(8,5,8)   DO_JOINT(9,6,9)
    DO_JOINT(10,7,10) DO_JOINT(11,8,11)
    DO_JOINT(12,9,12) DO_JOINT(13,9,13)
    CHUNK_FLUSH(1, 7,8,9,10,11,12,13)

    // ---- chunk 2: joints 14..20 ----
    DO_JOINT(14,9,14)  DO_JOINT(15,12,15) DO_JOINT(16,13,16)
    DO_JOINT(17,14,17) DO_JOINT(18,16,18)
    DO_JOINT(19,17,19) DO_JOINT(20,18,20)
    CHUNK_FLUSH(2, 14,15,16,17,18,19,20)
}

extern "C" void kernel_launch(void* const* d_in, const int* in_sizes, int n_in,
                              void* d_out, int out_size, void* d_ws, size_t ws_size,
                              hipStream_t stream) {
    const float* quat = (const float*)d_in[0];
    const float* W1r  = (const float*)d_in[1];
    const float* b1r  = (const float*)d_in[2];
    const float* W1   = (const float*)d_in[3];
    const float* b1   = (const float*)d_in[4];
    const float* W2   = (const float*)d_in[5];
    const float* b2   = (const float*)d_in[6];
    float* out = (float*)d_out;

    const int B = in_sizes[0] / (NJ * 4);
    const int threads = 256;
    const int blocks  = (B + threads - 1) / threads;
    se_kernel<<<blocks, threads, 0, stream>>>(quat, W1r, b1r, W1, b1, W2, b2, out, B);
}